// Round 10
// baseline (9023.948 us; speedup 1.0000x reference)
//
#include <hip/hip_runtime.h>
#include <math.h>

using floatx16 = __attribute__((ext_vector_type(16))) float;
using bf16x8   = __attribute__((ext_vector_type(8))) __bf16;
using ushort8  = __attribute__((ext_vector_type(8))) unsigned short;

// ---------- scalar helpers ----------
__device__ __forceinline__ float b2f(unsigned short u) {
  unsigned v = ((unsigned)u) << 16; float f; __builtin_memcpy(&f, &v, 4); return f;
}
__device__ __forceinline__ unsigned short f2b(float f) {
  unsigned u; __builtin_memcpy(&u, &f, 4);
  u += 0x7fffu + ((u >> 16) & 1u);          // RNE
  return (unsigned short)(u >> 16);
}
__device__ __forceinline__ float gelu_f(float x) {
  return 0.5f * x * (1.0f + erff(x * 0.7071067811865475f));
}
__device__ __forceinline__ float wred(float v) {
  #pragma unroll
  for (int off = 32; off > 0; off >>= 1) v += __shfl_xor(v, off, 64);
  return v;
}
__device__ __forceinline__ floatx16 zero16() {
  floatx16 z;
  #pragma unroll
  for (int e = 0; e < 16; e++) z[e] = 0.f;
  return z;
}

// XOR-swizzled LDS layout: 64-B rows (32 shorts), 16-B chunk c at slot c^(row&3).
// ~2-way max on writes and reads (free per m136). R9 lesson: global_load_lds DMA
// staging regressed (barrier's vmcnt(0) couples all staging latencies) — register
// staging + 1-barrier dbuf is the winning structure here.
#define SWZS(r, c) (((r) << 5) + ((((c) ^ ((r) & 3))) << 3))

// ---------- GEMM: C[M,N] = A[M,K] * Bt[N,K]^T  (TMx128 tiles, 32x32x16 MFMA, dbuf) ----------
// TM=128: 2 blocks/CU at grid 512 (big-M shapes with N>=1024)
// TM=64 : 4 blocks/CU at grid 1024 — latency-bound N=512 shapes
// MODE 0: +bias all rows, bf16 out            (context GEMMs, weight-combine)
// MODE 1: +bias all rows, gelu, bf16 out      (Wc1)
// MODE 2: +bias even rows (+bias2), bf16 out  (input GEMM, Wvo, Wm2)
// MODE 3: +bias even rows, gelu-JVP pairs     (Wp1)
template<int MODE, int TM>
__global__ __launch_bounds__(256) void gemm_bt_k(
    const unsigned short* __restrict__ A, const unsigned short* __restrict__ Bt,
    void* __restrict__ C, const float* __restrict__ bias,
    const float* __restrict__ bias2, int M, int N, int K)
{
  constexpr int TI = TM / 64;            // row sub-tiles per wave
  __shared__ unsigned short As[2 * TM * 32];
  __shared__ unsigned short Bs[2 * 128 * 32];
  const int tid  = threadIdx.x;
  const int lane = tid & 63;
  const int wave = tid >> 6;

  // XCD swizzle: contiguous row-panel range per XCD
  int bx = blockIdx.x, by = blockIdx.y;
  if ((gridDim.y & 7) == 0) {
    int lin = by * gridDim.x + bx;
    int xcd = lin & 7;
    int w   = lin >> 3;
    by = xcd * (gridDim.y >> 3) + w / gridDim.x;
    bx = w % gridDim.x;
  }
  const int row0 = by * TM;
  const int col0 = bx * 128;

  const int r0 = lane >> 2;              // 0..15
  const int cj = lane & 3;
  // A staging: wave covers TM/4 rows; TM==128 -> 2 loads (rows +0,+16), TM==64 -> 1
  const unsigned short* Ag = A  + (size_t)(row0 + wave * (TM / 4) + r0) * K + cj * 8;
  const unsigned short* Bg = Bt + (size_t)(col0 + wave * 32 + r0) * K + cj * 8;
  const int awA = SWZS(wave * (TM / 4) + r0, cj);
  const int awB = SWZS(wave * 32 + r0, cj);

  const int wr = wave >> 1, wc = wave & 1;
  const int m32 = lane & 31;
  const int hi  = lane >> 5;

  floatx16 acc[TI][2];
  #pragma unroll
  for (int i = 0; i < TI; i++) { acc[i][0] = zero16(); acc[i][1] = zero16(); }

  ushort8 ra0, ra1, rb0, rb1;
  ra0 = *(const ushort8*)(Ag);
  if (TM == 128) ra1 = *(const ushort8*)(Ag + (size_t)16 * K);
  rb0 = *(const ushort8*)(Bg);
  rb1 = *(const ushort8*)(Bg + (size_t)16 * K);

  int p = 0;
  for (int k0 = 0; k0 < K; k0 += 32) {
    unsigned short* Ab = &As[p * TM * 32];
    unsigned short* Bb = &Bs[p * 4096];
    *(ushort8*)(Ab + awA) = ra0;
    if (TM == 128) *(ushort8*)(Ab + awA + 16 * 32) = ra1;
    *(ushort8*)(Bb + awB)           = rb0;
    *(ushort8*)(Bb + awB + 16 * 32) = rb1;
    __syncthreads();
    if (k0 + 32 < K) {
      ra0 = *(const ushort8*)(Ag + k0 + 32);
      if (TM == 128) ra1 = *(const ushort8*)(Ag + (size_t)16 * K + k0 + 32);
      rb0 = *(const ushort8*)(Bg + k0 + 32);
      rb1 = *(const ushort8*)(Bg + (size_t)16 * K + k0 + 32);
    }
    bf16x8 af[TI][2], bfr[2][2];
    #pragma unroll
    for (int i = 0; i < TI; i++)
      #pragma unroll
      for (int h = 0; h < 2; h++)
        af[i][h] = *(const bf16x8*)&Ab[SWZS(wr * (TM / 2) + i * 32 + m32, 2 * h + hi)];
    #pragma unroll
    for (int j = 0; j < 2; j++)
      #pragma unroll
      for (int h = 0; h < 2; h++)
        bfr[j][h] = *(const bf16x8*)&Bb[SWZS(wc * 64 + j * 32 + m32, 2 * h + hi)];
    #pragma unroll
    for (int h = 0; h < 2; h++)
      #pragma unroll
      for (int i = 0; i < TI; i++)
        #pragma unroll
        for (int j = 0; j < 2; j++)
          acc[i][j] = __builtin_amdgcn_mfma_f32_32x32x16_bf16(af[i][h], bfr[j][h], acc[i][j], 0, 0, 0);
    p ^= 1;
  }

  #pragma unroll
  for (int j = 0; j < 2; j++) {
    int col = col0 + wc * 64 + j * 32 + m32;
    float bb = bias ? bias[col] : 0.f;
    if (MODE >= 2) { if (bias2) bb += bias2[col]; }
    #pragma unroll
    for (int i = 0; i < TI; i++) {
      int rb = row0 + wr * (TM / 2) + i * 32 + 4 * hi;
      if (MODE == 3) {
        #pragma unroll
        for (int pr = 0; pr < 8; pr++) {
          int re = rb + 2 * (pr & 1) + 8 * (pr >> 1);
          float pv = acc[i][j][2 * pr] + bb;       // primal (even row)
          float tv = acc[i][j][2 * pr + 1];        // tangent (odd row)
          float cdf = 0.5f * (1.0f + erff(pv * 0.7071067811865475f));
          float pdf = 0.3989422804014327f * expf(-0.5f * pv * pv);
          ((unsigned short*)C)[(size_t)re * N + col]       = f2b(pv * cdf);
          ((unsigned short*)C)[(size_t)(re + 1) * N + col] = f2b((cdf + pv * pdf) * tv);
        }
      } else {
        #pragma unroll
        for (int reg = 0; reg < 16; reg++) {
          int row = rb + (reg & 3) + 8 * (reg >> 2);
          float v = acc[i][j][reg];
          if (MODE == 0 || MODE == 1) v += bb;
          if (MODE == 2) { if ((reg & 1) == 0) v += bb; }   // even rows
          if (MODE == 1) v = gelu_f(v);
          ((unsigned short*)C)[(size_t)row * N + col] = f2b(v);
        }
      }
    }
  }
}

// ---------- wide GEMM for Wm1: 128x256 tile, wave 64x128, gelu-JVP epilogue ----------
__global__ __launch_bounds__(256, 2) void gemm_wide3_k(
    const unsigned short* __restrict__ A, const unsigned short* __restrict__ Bt,
    unsigned short* __restrict__ C, const float* __restrict__ bias,
    int M, int N, int K)
{
  __shared__ unsigned short As[2 * 128 * 32];   // 16 KB
  __shared__ unsigned short Bs[2 * 256 * 32];   // 32 KB
  const int tid  = threadIdx.x;
  const int lane = tid & 63;
  const int wave = tid >> 6;

  int bx = blockIdx.x, by = blockIdx.y;
  if ((gridDim.y & 7) == 0) {
    int lin = by * gridDim.x + bx;
    int xcd = lin & 7;
    int w   = lin >> 3;
    by = xcd * (gridDim.y >> 3) + w / gridDim.x;
    bx = w % gridDim.x;
  }
  const int row0 = by * 128;
  const int col0 = bx * 256;

  const int r0 = lane >> 2;
  const int cj = lane & 3;
  const unsigned short* Ag = A  + (size_t)(row0 + wave * 32 + r0) * K + cj * 8;
  const unsigned short* Bg = Bt + (size_t)(col0 + wave * 64 + r0) * K + cj * 8;
  const int awr = wave * 32 + r0;
  const int bwr = wave * 64 + r0;

  const int wr = wave >> 1, wc = wave & 1;
  const int m32 = lane & 31;
  const int hi  = lane >> 5;

  floatx16 acc[2][4];
  #pragma unroll
  for (int i = 0; i < 2; i++)
    #pragma unroll
    for (int j = 0; j < 4; j++) acc[i][j] = zero16();

  ushort8 ra0, ra1, rbv[4];
  ra0 = *(const ushort8*)(Ag);
  ra1 = *(const ushort8*)(Ag + (size_t)16 * K);
  #pragma unroll
  for (int t = 0; t < 4; t++)
    rbv[t] = *(const ushort8*)(Bg + (size_t)16 * t * K);

  int p = 0;
  for (int k0 = 0; k0 < K; k0 += 32) {
    unsigned short* Ab = &As[p * 4096];
    unsigned short* Bb = &Bs[p * 8192];
    *(ushort8*)&Ab[SWZS(awr, cj)]      = ra0;
    *(ushort8*)&Ab[SWZS(awr + 16, cj)] = ra1;
    #pragma unroll
    for (int t = 0; t < 4; t++)
      *(ushort8*)&Bb[SWZS(bwr + 16 * t, cj)] = rbv[t];
    __syncthreads();
    if (k0 + 32 < K) {
      ra0 = *(const ushort8*)(Ag + k0 + 32);
      ra1 = *(const ushort8*)(Ag + (size_t)16 * K + k0 + 32);
      #pragma unroll
      for (int t = 0; t < 4; t++)
        rbv[t] = *(const ushort8*)(Bg + (size_t)16 * t * K + k0 + 32);
    }
    bf16x8 af[2][2], bfr[4][2];
    #pragma unroll
    for (int i = 0; i < 2; i++)
      #pragma unroll
      for (int h = 0; h < 2; h++)
        af[i][h] = *(const bf16x8*)&Ab[SWZS(wr * 64 + i * 32 + m32, 2 * h + hi)];
    #pragma unroll
    for (int j = 0; j < 4; j++)
      #pragma unroll
      for (int h = 0; h < 2; h++)
        bfr[j][h] = *(const bf16x8*)&Bb[SWZS(wc * 128 + j * 32 + m32, 2 * h + hi)];
    #pragma unroll
    for (int h = 0; h < 2; h++)
      #pragma unroll
      for (int i = 0; i < 2; i++)
        #pragma unroll
        for (int j = 0; j < 4; j++)
          acc[i][j] = __builtin_amdgcn_mfma_f32_32x32x16_bf16(af[i][h], bfr[j][h], acc[i][j], 0, 0, 0);
    p ^= 1;
  }

  #pragma unroll
  for (int j = 0; j < 4; j++) {
    int col = col0 + wc * 128 + j * 32 + m32;
    float bb = bias[col];
    #pragma unroll
    for (int i = 0; i < 2; i++) {
      int rb = row0 + wr * 64 + i * 32 + 4 * hi;
      #pragma unroll
      for (int pr = 0; pr < 8; pr++) {
        int re = rb + 2 * (pr & 1) + 8 * (pr >> 1);
        float pv = acc[i][j][2 * pr] + bb;
        float tv = acc[i][j][2 * pr + 1];
        float cdf = 0.5f * (1.0f + erff(pv * 0.7071067811865475f));
        float pdf = 0.3989422804014327f * expf(-0.5f * pv * pv);
        C[(size_t)re * N + col]       = f2b(pv * cdf);
        C[(size_t)(re + 1) * N + col] = f2b((cdf + pv * pdf) * tv);
      }
    }
  }
}

// ---------- fused Wp2 GEMM + Euler update + Hutchinson + Abuf build (dbuf) ----------
__global__ __launch_bounds__(256) void gemm_vout_k(
    const unsigned short* __restrict__ A, const unsigned short* __restrict__ Bt,
    const float* __restrict__ bias, const float* __restrict__ u_cur,
    const float* __restrict__ u_next, float* __restrict__ zf,
    float* __restrict__ ldb, unsigned short* __restrict__ Abuf,
    int K, float dtv)
{
  constexpr int N = 128;
  __shared__ unsigned short As[2 * 128 * 32];
  __shared__ unsigned short Bs[2 * 128 * 32];
  __shared__ float red[64][2];
  const int tid = threadIdx.x, lane = tid & 63, wave = tid >> 6;
  const int row0 = blockIdx.x * 128;

  const int r0 = lane >> 2;
  const int cj = lane & 3;
  const unsigned short* Ag = A  + (size_t)(row0 + wave * 32 + r0) * K + cj * 8;
  const unsigned short* Bg = Bt + (size_t)(wave * 32 + r0) * K + cj * 8;
  const int aw0 = SWZS(wave * 32 + r0, cj);

  const int wr = wave >> 1, wc = wave & 1;
  const int m32 = lane & 31;
  const int hi  = lane >> 5;

  floatx16 acc[2][2];
  acc[0][0] = zero16(); acc[0][1] = zero16();
  acc[1][0] = zero16(); acc[1][1] = zero16();

  ushort8 ra0, ra1, rb0, rb1;
  ra0 = *(const ushort8*)(Ag);
  ra1 = *(const ushort8*)(Ag + (size_t)16 * K);
  rb0 = *(const ushort8*)(Bg);
  rb1 = *(const ushort8*)(Bg + (size_t)16 * K);

  int p = 0;
  for (int k0 = 0; k0 < K; k0 += 32) {
    unsigned short* Ab = &As[p * 4096];
    unsigned short* Bb = &Bs[p * 4096];
    *(ushort8*)(Ab + aw0)           = ra0;
    *(ushort8*)(Ab + aw0 + 16 * 32) = ra1;
    *(ushort8*)(Bb + aw0)           = rb0;
    *(ushort8*)(Bb + aw0 + 16 * 32) = rb1;
    __syncthreads();
    if (k0 + 32 < K) {
      ra0 = *(const ushort8*)(Ag + k0 + 32);
      ra1 = *(const ushort8*)(Ag + (size_t)16 * K + k0 + 32);
      rb0 = *(const ushort8*)(Bg + k0 + 32);
      rb1 = *(const ushort8*)(Bg + (size_t)16 * K + k0 + 32);
    }
    bf16x8 af[2][2], bfr[2][2];
    #pragma unroll
    for (int i = 0; i < 2; i++)
      #pragma unroll
      for (int h = 0; h < 2; h++)
        af[i][h] = *(const bf16x8*)&Ab[SWZS(wr * 64 + i * 32 + m32, 2 * h + hi)];
    #pragma unroll
    for (int j = 0; j < 2; j++)
      #pragma unroll
      for (int h = 0; h < 2; h++)
        bfr[j][h] = *(const bf16x8*)&Bb[SWZS(wc * 64 + j * 32 + m32, 2 * h + hi)];
    #pragma unroll
    for (int h = 0; h < 2; h++)
      #pragma unroll
      for (int i = 0; i < 2; i++)
        #pragma unroll
        for (int j = 0; j < 2; j++)
          acc[i][j] = __builtin_amdgcn_mfma_f32_32x32x16_bf16(af[i][h], bfr[j][h], acc[i][j], 0, 0, 0);
    p ^= 1;
  }

  #pragma unroll
  for (int i = 0; i < 2; i++) {
    #pragma unroll
    for (int pr = 0; pr < 8; pr++) {
      int re_loc = wr * 64 + i * 32 + 4 * hi + 2 * (pr & 1) + 8 * (pr >> 1);
      size_t growe = (size_t)(row0 + re_loc);
      size_t b = growe >> 1;           // pair (batch row) index
      float dacc = 0.f;
      #pragma unroll
      for (int j = 0; j < 2; j++) {
        int col = wc * 64 + j * 32 + m32;
        float v  = acc[i][j][2 * pr] + bias[col];
        float Ju = acc[i][j][2 * pr + 1];
        float z = zf[b * N + col] + v * dtv;
        zf[b * N + col] = z;
        Abuf[growe * N + col] = f2b(z);
        if (u_next) Abuf[(growe + 1) * N + col] = f2b(u_next[b * N + col]);
        dacc += u_cur[b * N + col] * Ju;
      }
      #pragma unroll
      for (int off = 1; off <= 16; off <<= 1) dacc += __shfl_xor(dacc, off, 64);
      if (m32 == 0) red[re_loc >> 1][wc] = dacc;
    }
  }
  __syncthreads();
  if (tid < 64) ldb[(row0 >> 1) + tid] += (red[tid][0] + red[tid][1]) * dtv;
}

// ---------- LN-JVP; interleaved pair rows (2w, 2w+1), in-place on h ----------
__global__ __launch_bounds__(256) void ln_jvp_k(
    unsigned short* h, const unsigned short* __restrict__ r,
    const float* __restrict__ g, const float* __restrict__ be,
    const unsigned short* __restrict__ xatt, const float* __restrict__ sc_p,
    int Bhalf, int H)
{
  int gw = (int)((blockIdx.x * blockDim.x + threadIdx.x) >> 6);
  int lane = threadIdx.x & 63;
  if (gw >= Bhalf) return;
  int c0 = lane * 8;
  size_t op = (size_t)(2 * gw) * H + c0;
  size_t ot = op + H;
  ushort8 hp = *(const ushort8*)&h[op];
  ushort8 ht = *(const ushort8*)&h[ot];
  ushort8 rp = *(const ushort8*)&r[op];
  ushort8 rt = *(const ushort8*)&r[ot];
  float xv[8], dv[8];
  float s1 = 0.f, s2 = 0.f, sd = 0.f;
  #pragma unroll
  for (int j = 0; j < 8; j++) {
    xv[j] = b2f(hp[j]) + b2f(rp[j]);
    dv[j] = b2f(ht[j]) + b2f(rt[j]);
    s1 += xv[j]; s2 += xv[j] * xv[j]; sd += dv[j];
  }
  s1 = wred(s1); s2 = wred(s2); sd = wred(sd);
  float inv = 1.0f / (float)H;
  float m = s1 * inv;
  float var = s2 * inv - m * m;
  float rstd = rsqrtf(var + 1e-5f);
  float dm = sd * inv;
  float c = 0.f;
  #pragma unroll
  for (int j = 0; j < 8; j++) c += (xv[j] - m) * dv[j];
  c = wred(c);
  float cm = c * inv * rstd;  // mean(xhat * dx)
  float sl = sc_p ? *sc_p : 0.f;
  ushort8 oy, od;
  #pragma unroll
  for (int j = 0; j < 8; j++) {
    float xh = (xv[j] - m) * rstd;
    float gg = g[c0 + j];
    float y = xh * gg + be[c0 + j];
    if (xatt) y += sl * b2f(xatt[(size_t)gw * H + c0 + j]);
    float dy = gg * rstd * (dv[j] - dm - xh * cm);
    oy[j] = f2b(y); od[j] = f2b(dy);
  }
  *(ushort8*)&h[op] = oy;
  *(ushort8*)&h[ot] = od;
}

// ---------- transpose+cast: W[K,N] f32 -> Wt[N,K] bf16 (batched over z) ----------
__global__ void transpose_cast_k(const float* __restrict__ W,
                                 unsigned short* __restrict__ Wt, int K, int N)
{
  __shared__ float tile[32][33];
  size_t off = (size_t)blockIdx.z * K * N;
  const float* Wp = W + off;
  unsigned short* Wtp = Wt + off;
  int bx = blockIdx.x, by = blockIdx.y;
  int tx = threadIdx.x, ty = threadIdx.y;
  #pragma unroll
  for (int i = ty; i < 32; i += 8)
    tile[i][tx] = Wp[(size_t)(by * 32 + i) * N + bx * 32 + tx];
  __syncthreads();
  #pragma unroll
  for (int i = ty; i < 32; i += 8)
    Wtp[(size_t)(bx * 32 + i) * K + by * 32 + tx] = f2b(tile[tx][i]);
}

// ---------- zero-init ----------
__global__ __launch_bounds__(256) void zero_k(float* __restrict__ p, int n) {
  int i = (int)(blockIdx.x * blockDim.x + threadIdx.x);
  if (i < n) p[i] = 0.f;
}

// ---------- combined bias (k-split + atomics) ----------
__global__ __launch_bounds__(256) void combine_bias_k(
    const float* __restrict__ bvp, const float* __restrict__ Wb,
    const float* __restrict__ bo, float* __restrict__ bout, int H)
{
  int out = blockIdx.x * blockDim.x + threadIdx.x;
  int l   = blockIdx.y;
  int kc  = blockIdx.z;
  const float* A2 = Wb + (size_t)l * H * H;
  float s = (kc == 0) ? bo[(size_t)l * H + out] : 0.f;
  int kend = (kc + 1) * 64;
  for (int k = kc * 64; k < kend; k++) s += bvp[(size_t)l * H + k] * A2[(size_t)k * H + out];
  atomicAdd(&bout[(size_t)l * H + out], s);
}

// ---------- f32 -> bf16 cast ----------
__global__ __launch_bounds__(256) void cast_k(const float* __restrict__ in,
                                              unsigned short* __restrict__ out, size_t n) {
  size_t i = blockIdx.x * blockDim.x + threadIdx.x;
  if (i < n) out[i] = f2b(in[i]);
}

// ---------- all S time embeddings: tvecs[s][H] ----------
__global__ __launch_bounds__(512) void temb_all_k(
    const float* __restrict__ Wt1, const float* __restrict__ bt1,
    const float* __restrict__ Wt2, const float* __restrict__ bt2,
    float dtv, float* __restrict__ tvecs, int H)
{
  __shared__ float e[512];
  int j = threadIdx.x;
  float t = fminf(fmaxf((float)blockIdx.x * dtv, 0.f), 1.f);
  e[j] = gelu_f(t * Wt1[j] + bt1[j]);
  __syncthreads();
  float s = bt2[j];
  for (int k = 0; k < H; k++) s += e[k] * Wt2[(size_t)k * H + j];
  tvecs[(size_t)blockIdx.x * H + j] = s;
}

// ---------- init: zf=x, ld=0, Abuf interleaved [z;u] ----------
__global__ __launch_bounds__(256) void init_k(
    const float* __restrict__ x, const float* __restrict__ u0,
    float* __restrict__ zf, float* __restrict__ ld,
    unsigned short* __restrict__ Abuf, int BF, int Bsz, int F)
{
  int i = (int)(blockIdx.x * blockDim.x + threadIdx.x);
  if (i < BF) {
    int r = i / F, c = i - r * F;
    float v = x[i];
    zf[i] = v;
    Abuf[(size_t)(2 * r) * F + c]     = f2b(v);
    Abuf[(size_t)(2 * r + 1) * F + c] = f2b(u0[i]);
  }
  if (i < Bsz) ld[i] = 0.f;
}

// ---------- write outputs ----------
__global__ __launch_bounds__(256) void final_k(
    const float* __restrict__ zf, const float* __restrict__ ld,
    float* __restrict__ out, int BF, int Bsz)
{
  int i = (int)(blockIdx.x * blockDim.x + threadIdx.x);
  if (i < BF) out[i] = zf[i];
  if (i < Bsz) out[BF + i] = ld[i];
}

extern "C" void kernel_launch(void* const* d_in, const int* in_sizes, int n_in,
                              void* d_out, int out_size, void* d_ws, size_t ws_size,
                              hipStream_t stream) {
  constexpr int B = 8192, F = 128, C = 256, H = 512, L = 4, S = 10;
  constexpr int B2 = 2 * B;
  constexpr int BF = B * F;
  const float dtv = 1.0f / S;

  const float* x    = (const float*)d_in[0];
  const float* ctxI = (const float*)d_in[1];
  const float* u    = (const float*)d_in[2];
  const float* Wi   = (const float*)d_in[3];
  const float* bi   = (const float*)d_in[4];
  const float* Wt1  = (const float*)d_in[5];
  const float* bt1  = (const float*)d_in[6];
  const float* Wt2  = (const float*)d_in[7];
  const float* bt2  = (const float*)d_in[8];
  const float* Wc1  = (const float*)d_in[9];
  const float* bc1  = (const float*)d_in[10];
  const float* Wc2  = (const float*)d_in[11];
  const float* bc2  = (const float*)d_in[12];
  const float* Wv   = (const float*)d_in[13];
  const float* bv   = (const float*)d_in[14];
  const float* Woa  = (const float*)d_in[15];
  const float* boa  = (const float*)d_in[16];
  const float* g1   = (const float*)d_in[17];
  const float* be1  = (const float*)d_in[18];
  const float* Wm1  = (const float*)d_in[19];
  const float* bm1  = (const float*)d_in[20];
  const float* Wm2  = (const float*)d_in[21];
  const float* bm2  = (const float*)d_in[22];
  const float* g2   = (const float*)d_in[23];
  const float* be2  = (const float*)d_in[24];
  const float* Wcv  = (const float*)d_in[25];
  const float* bcv  = (const float*)d_in[26];
  const float* Wco  = (const float*)d_in[27];
  const float* bco  = (const float*)d_in[28];
  const float* scal = (const float*)d_in[29];
  const float* Wp1  = (const float*)d_in[30];
  const float* bp1  = (const float*)d_in[31];
  const float* Wp2  = (const float*)d_in[32];
  const float* bp2  = (const float*)d_in[33];

  // ---- workspace layout ----
  char* wp = (char*)d_ws;
  auto alloc = [&](size_t bytes) -> void* {
    void* r = (void*)wp;
    wp += (bytes + 255) & ~(size_t)255;
    return r;
  };
  unsigned short* wWit  = (unsigned short*)alloc((size_t)H * F * 2);
  unsigned short* wWc1t = (unsigned short*)alloc((size_t)2 * H * C * 2);
  unsigned short* wWc2t = (unsigned short*)alloc((size_t)H * 2 * H * 2);
  unsigned short* wWvoT = (unsigned short*)alloc((size_t)L * H * H * 2);
  unsigned short* wCtxT = (unsigned short*)alloc((size_t)L * H * H * 2);
  unsigned short* wWm1t = (unsigned short*)alloc((size_t)L * 4 * H * H * 2);
  unsigned short* wWm2t = (unsigned short*)alloc((size_t)L * H * 4 * H * 2);
  unsigned short* wWp1t = (unsigned short*)alloc((size_t)H * H * 2);
  unsigned short* wWp2t = (unsigned short*)alloc((size_t)F * H * 2);
  unsigned short* wOaT  = (unsigned short*)alloc((size_t)L * H * H * 2);
  unsigned short* wCoT  = (unsigned short*)alloc((size_t)L * H * H * 2);
  unsigned short* wVb   = (unsigned short*)alloc((size_t)L * H * H * 2);
  unsigned short* wCvb  = (unsigned short*)alloc((size_t)L * H * H * 2);
  float* bcomb          = (float*)alloc((size_t)2 * L * H * 4);  // bvo | cbvo
  float* bvo  = bcomb;
  float* cbvo = bcomb + (size_t)L * H;
  float* tvecs          = (float*)alloc((size_t)S * H * 4);
  unsigned short* ctxc  = (unsigned short*)alloc((size_t)B * C * 2);
  unsigned short* Abuf  = (unsigned short*)alloc((size_t)B2 * F * 2);
  unsigned short* hbuf  = (unsigned short*)alloc((size_t)B2 * H * 2);
  unsigned short* tmp2  = (unsigned short*)alloc((size_t)B2 * H * 2);
  unsigned short* mbuf  = (unsigned short*)alloc((size_t)B2 * 4 * H * 2);
  unsigned short* xattb = (unsigned short*)alloc((size_t)L * B * H * 2);
  float* zf             = (float*)alloc((size_t)B * F * 4);
  float* ldb            = (float*)alloc((size_t)B * 4);
  (void)ws_size; (void)in_sizes; (void)n_in; (void)out_size;

  auto T = [&](const float* W, unsigned short* Wt, int K, int N, int Lz) {
    dim3 g(N / 32, K / 32, Lz);
    transpose_cast_k<<<g, dim3(32, 8), 0, stream>>>(W, Wt, K, N);
  };
  // tm=64 for latency-bound N=512 shapes (grid 1024 -> 4 blocks/CU), 128 otherwise
  auto G = [&](int mode, int tm, const unsigned short* A, const unsigned short* Bt, void* Cc,
               const float* bias, const float* bias2, int M, int N, int K) {
    if (tm == 64) {
      dim3 g(N / 128, M / 64);
      switch (mode) {
        case 0: gemm_bt_k<0, 64><<<g, 256, 0, stream>>>(A, Bt, Cc, bias, bias2, M, N, K); break;
        case 2: gemm_bt_k<2, 64><<<g, 256, 0, stream>>>(A, Bt, Cc, bias, bias2, M, N, K); break;
        case 3: gemm_bt_k<3, 64><<<g, 256, 0, stream>>>(A, Bt, Cc, bias, bias2, M, N, K); break;
      }
    } else {
      dim3 g(N / 128, M / 128);
      switch (mode) {
        case 0: gemm_bt_k<0, 128><<<g, 256, 0, stream>>>(A, Bt, Cc, bias, bias2, M, N, K); break;
        case 1: gemm_bt_k<1, 128><<<g, 256, 0, stream>>>(A, Bt, Cc, bias, bias2, M, N, K); break;
        case 2: gemm_bt_k<2, 128><<<g, 256, 0, stream>>>(A, Bt, Cc, bias, bias2, M, N, K); break;
        case 3: gemm_bt_k<3, 128><<<g, 256, 0, stream>>>(A, Bt, Cc, bias, bias2, M, N, K); break;
      }
    }
  };

  // ---- weight prep ----
  T(Wi,  wWit,  F, H, 1);
  T(Wc1, wWc1t, C, 2 * H, 1);
  T(Wc2, wWc2t, 2 * H, H, 1);
  T(Wm1, wWm1t, H, 4 * H, L);
  T(Wm2, wWm2t, 4 * H, H, L);
  T(Wp1, wWp1t, H, H, 1);
  T(Wp2, wWp2t, H, F, 1);
  T(Woa, wOaT, H, H, L);
  T(Wco, wCoT, H, H, L);
  cast_k<<<((size_t)L * H * H + 255) / 256, 256, 0, stream>>>(Wv,  wVb,  (size_t)L * H * H);
  cast_k<<<((size_t)L * H * H + 255) / 256, 256, 0, stream>>>(Wcv, wCvb, (size_t)L * H * H);
  for (int l = 0; l < L; l++) {
    size_t o2 = (size_t)l * H * H;
    G(0, 128, wOaT + o2, wVb  + o2, wWvoT + o2, nullptr, nullptr, H, H, H);
    G(0, 128, wCoT + o2, wCvb + o2, wCtxT + o2, nullptr, nullptr, H, H, H);
  }
  zero_k<<<(2 * L * H + 255) / 256, 256, 0, stream>>>(bcomb, 2 * L * H);
  combine_bias_k<<<dim3(H / 256, L, H / 64), 256, 0, stream>>>(bv,  Woa, boa, bvo,  H);
  combine_bias_k<<<dim3(H / 256, L, H / 64), 256, 0, stream>>>(bcv, Wco, bco, cbvo, H);

  // ---- context path (z-independent): xatt[l] = ctx @ (Wcv@Wco) + (bcv@Wco+bco) ----
  cast_k<<<(B * C + 255) / 256, 256, 0, stream>>>(ctxI, ctxc, (size_t)B * C);
  G(1, 128, ctxc, wWc1t, mbuf, bc1, nullptr, B, 2 * H, C);      // gelu fused
  G(0, 64, mbuf, wWc2t, tmp2, bc2, nullptr, B, H, 2 * H);
  for (int l = 0; l < L; l++)
    G(0, 64, tmp2, wCtxT + (size_t)l * H * H, xattb + (size_t)l * B * H,
      cbvo + l * H, nullptr, B, H, H);

  temb_all_k<<<S, H, 0, stream>>>(Wt1, bt1, Wt2, bt2, dtv, tvecs, H);
  init_k<<<(BF + 255) / 256, 256, 0, stream>>>(x, u, zf, ldb, Abuf, BF, B, F);

  // ---- S Euler steps; rows interleaved (2i primal, 2i+1 tangent) ----
  for (int s = 0; s < S; s++) {
    G(2, 64, Abuf, wWit, hbuf, bi, tvecs + (size_t)s * H, B2, H, F);
    for (int l = 0; l < L; l++) {
      size_t o2 = (size_t)l * H * H;
      size_t om = (size_t)l * 4 * H * H;
      G(2, 64, hbuf, wWvoT + o2, tmp2, bvo + l * H, nullptr, B2, H, H);  // fused attn
      ln_jvp_k<<<B / 4, 256, 0, stream>>>(hbuf, tmp2, g1 + l * H, be1 + l * H,
                                          nullptr, nullptr, B, H);
      gemm_wide3_k<<<dim3(4 * H / 256, B2 / 128), 256, 0, stream>>>(
          hbuf, wWm1t + om, mbuf, bm1 + (size_t)l * 4 * H, B2, 4 * H, H);
      G(2, 64, mbuf, wWm2t + om, tmp2, bm2 + l * H, nullptr, B2, H, 4 * H);
      ln_jvp_k<<<B / 4, 256, 0, stream>>>(hbuf, tmp2, g2 + l * H, be2 + l * H,
                                          xattb + (size_t)l * B * H, scal + l, B, H);
    }
    G(3, 64, hbuf, wWp1t, tmp2, bp1, nullptr, B2, H, H);
    const float* u_cur = u + (size_t)s * BF;
    const float* u_next = (s + 1 < S) ? u + (size_t)(s + 1) * BF : nullptr;
    gemm_vout_k<<<B2 / 128, 256, 0, stream>>>(
        tmp2, wWp2t, bp2, u_cur, u_next, zf, ldb, Abuf, H, dtv);
  }

  final_k<<<(BF + 255) / 256, 256, 0, stream>>>(zf, ldb, (float*)d_out, BF, B);
}

// Round 11
// 7796.931 us; speedup vs baseline: 1.1574x; 1.1574x over previous
//
#include <hip/hip_runtime.h>
#include <math.h>

using floatx16 = __attribute__((ext_vector_type(16))) float;
using bf16x8   = __attribute__((ext_vector_type(8))) __bf16;
using ushort8  = __attribute__((ext_vector_type(8))) unsigned short;

// ---------- scalar helpers ----------
__device__ __forceinline__ float b2f(unsigned short u) {
  unsigned v = ((unsigned)u) << 16; float f; __builtin_memcpy(&f, &v, 4); return f;
}
__device__ __forceinline__ unsigned short f2b(float f) {
  unsigned u; __builtin_memcpy(&u, &f, 4);
  u += 0x7fffu + ((u >> 16) & 1u);          // RNE
  return (unsigned short)(u >> 16);
}
__device__ __forceinline__ float gelu_f(float x) {
  return 0.5f * x * (1.0f + erff(x * 0.7071067811865475f));
}
__device__ __forceinline__ floatx16 zero16() {
  floatx16 z;
  #pragma unroll
  for (int e = 0; e < 16; e++) z[e] = 0.f;
  return z;
}

// XOR-swizzled LDS layout: 64-B rows (32 shorts), 16-B chunk c at slot c^(row&3).
// ~2-way max on writes and reads (free per m136).
// R9 lesson: global_load_lds DMA staging regressed (barrier vmcnt(0) couples all
// staging latencies). R10 lesson: TM=64 duplicates B staging — net loss.
#define SWZS(r, c) (((r) << 5) + ((((c) ^ ((r) & 3))) << 3))

// ---------- GEMM: C[M,N] = A[M,K] * Bt[N,K]^T  (128x128, 32x32x16 MFMA, dbuf) ----------
// MODE 0: +bias all rows, bf16 out            (context GEMMs, weight-combine)
// MODE 1: +bias all rows, gelu, bf16 out      (Wc1)
// MODE 2: +bias even rows (+bias2), bf16 out  (input GEMM)
// MODE 3: +bias even rows, gelu-JVP pairs     (Wp1)
template<int MODE>
__global__ __launch_bounds__(256) void gemm_bt_k(
    const unsigned short* __restrict__ A, const unsigned short* __restrict__ Bt,
    void* __restrict__ C, const float* __restrict__ bias,
    const float* __restrict__ bias2, int M, int N, int K)
{
  __shared__ unsigned short As[2 * 128 * 32];   // 16 KB
  __shared__ unsigned short Bs[2 * 128 * 32];
  const int tid  = threadIdx.x;
  const int lane = tid & 63;
  const int wave = tid >> 6;

  // XCD swizzle: contiguous row-panel range per XCD
  int bx = blockIdx.x, by = blockIdx.y;
  if ((gridDim.y & 7) == 0) {
    int lin = by * gridDim.x + bx;
    int xcd = lin & 7;
    int w   = lin >> 3;
    by = xcd * (gridDim.y >> 3) + w / gridDim.x;
    bx = w % gridDim.x;
  }
  const int row0 = by * 128;
  const int col0 = bx * 128;

  const int r0 = lane >> 2;
  const int cj = lane & 3;
  const unsigned short* Ag = A  + (size_t)(row0 + wave * 32 + r0) * K + cj * 8;
  const unsigned short* Bg = Bt + (size_t)(col0 + wave * 32 + r0) * K + cj * 8;
  const int aw0 = SWZS(wave * 32 + r0, cj);

  const int wr = wave >> 1, wc = wave & 1;
  const int m32 = lane & 31;
  const int hi  = lane >> 5;

  floatx16 acc[2][2];
  acc[0][0] = zero16(); acc[0][1] = zero16();
  acc[1][0] = zero16(); acc[1][1] = zero16();

  ushort8 ra0, ra1, rb0, rb1;
  ra0 = *(const ushort8*)(Ag);
  ra1 = *(const ushort8*)(Ag + (size_t)16 * K);
  rb0 = *(const ushort8*)(Bg);
  rb1 = *(const ushort8*)(Bg + (size_t)16 * K);

  int p = 0;
  for (int k0 = 0; k0 < K; k0 += 32) {
    unsigned short* Ab = &As[p * 4096];
    unsigned short* Bb = &Bs[p * 4096];
    *(ushort8*)(Ab + aw0)            = ra0;
    *(ushort8*)(Ab + aw0 + 16 * 32)  = ra1;
    *(ushort8*)(Bb + aw0)            = rb0;
    *(ushort8*)(Bb + aw0 + 16 * 32)  = rb1;
    __syncthreads();
    if (k0 + 32 < K) {
      ra0 = *(const ushort8*)(Ag + k0 + 32);
      ra1 = *(const ushort8*)(Ag + (size_t)16 * K + k0 + 32);
      rb0 = *(const ushort8*)(Bg + k0 + 32);
      rb1 = *(const ushort8*)(Bg + (size_t)16 * K + k0 + 32);
    }
    bf16x8 af[2][2], bfr[2][2];
    #pragma unroll
    for (int i = 0; i < 2; i++)
      #pragma unroll
      for (int h = 0; h < 2; h++)
        af[i][h] = *(const bf16x8*)&Ab[SWZS(wr * 64 + i * 32 + m32, 2 * h + hi)];
    #pragma unroll
    for (int j = 0; j < 2; j++)
      #pragma unroll
      for (int h = 0; h < 2; h++)
        bfr[j][h] = *(const bf16x8*)&Bb[SWZS(wc * 64 + j * 32 + m32, 2 * h + hi)];
    #pragma unroll
    for (int h = 0; h < 2; h++)
      #pragma unroll
      for (int i = 0; i < 2; i++)
        #pragma unroll
        for (int j = 0; j < 2; j++)
          acc[i][j] = __builtin_amdgcn_mfma_f32_32x32x16_bf16(af[i][h], bfr[j][h], acc[i][j], 0, 0, 0);
    p ^= 1;
  }

  #pragma unroll
  for (int j = 0; j < 2; j++) {
    int col = col0 + wc * 64 + j * 32 + m32;
    float bb = bias ? bias[col] : 0.f;
    if (MODE >= 2) { if (bias2) bb += bias2[col]; }
    #pragma unroll
    for (int i = 0; i < 2; i++) {
      int rb = row0 + wr * 64 + i * 32 + 4 * hi;
      if (MODE == 3) {
        #pragma unroll
        for (int pr = 0; pr < 8; pr++) {
          int re = rb + 2 * (pr & 1) + 8 * (pr >> 1);
          float pv = acc[i][j][2 * pr] + bb;       // primal (even row)
          float tv = acc[i][j][2 * pr + 1];        // tangent (odd row)
          float cdf = 0.5f * (1.0f + erff(pv * 0.7071067811865475f));
          float pdf = 0.3989422804014327f * expf(-0.5f * pv * pv);
          ((unsigned short*)C)[(size_t)re * N + col]       = f2b(pv * cdf);
          ((unsigned short*)C)[(size_t)(re + 1) * N + col] = f2b((cdf + pv * pdf) * tv);
        }
      } else {
        #pragma unroll
        for (int reg = 0; reg < 16; reg++) {
          int row = rb + (reg & 3) + 8 * (reg >> 2);
          float v = acc[i][j][reg];
          if (MODE == 0 || MODE == 1) v += bb;
          if (MODE == 2) { if ((reg & 1) == 0) v += bb; }   // even rows
          if (MODE == 1) v = gelu_f(v);
          ((unsigned short*)C)[(size_t)row * N + col] = f2b(v);
        }
      }
    }
  }
}

// ---------- fused GEMM + residual + LN-JVP (+xatt), in-place on h ----------
// Block = 64 rows x 512 cols (full N), grid = M/64 = 256 = 1 block/CU.
// Owns complete rows -> LN block-local; owns its A rows -> in-place safe.
// dbuf + register staging + SWZS (R5's failure was 16-way conflicts + 32-row blocks).
template<bool XATT>
__global__ __launch_bounds__(256) void gemm_ln_k(
    const unsigned short* __restrict__ A, const unsigned short* __restrict__ Bt,
    unsigned short* __restrict__ h, const float* __restrict__ bias,
    const float* __restrict__ g, const float* __restrict__ be,
    const unsigned short* __restrict__ xatt, const float* __restrict__ sc_p,
    int K)
{
  constexpr int N = 512;
  __shared__ unsigned short As[2 * 64 * 32];     // 8 KB
  __shared__ unsigned short Bs[2 * 512 * 32];    // 64 KB
  __shared__ float red[32][2][4];                // [pair][wc][sx,sxx,sdv,sxdv]
  const int tid = threadIdx.x, lane = tid & 63, wave = tid >> 6;
  const int row0 = blockIdx.x * 64;

  const int r0 = lane >> 2;
  const int cj = lane & 3;
  const unsigned short* Ag = A + (size_t)(row0 + wave * 16 + r0) * K + cj * 8;
  const int awA = SWZS(wave * 16 + r0, cj);
  const unsigned short* Bg = Bt + (size_t)(wave * 128 + r0) * K + cj * 8;
  const int bwr = wave * 128 + r0;

  const int wr = wave >> 1, wc = wave & 1;       // wave = 32 rows x 256 cols
  const int m32 = lane & 31;
  const int hi  = lane >> 5;

  floatx16 acc[8];
  #pragma unroll
  for (int j = 0; j < 8; j++) acc[j] = zero16();

  ushort8 ra0, rbv[8];
  ra0 = *(const ushort8*)(Ag);
  #pragma unroll
  for (int t = 0; t < 8; t++)
    rbv[t] = *(const ushort8*)(Bg + (size_t)16 * t * K);

  int p = 0;
  for (int k0 = 0; k0 < K; k0 += 32) {
    unsigned short* Ab = &As[p * 2048];
    unsigned short* Bb = &Bs[p * 16384];
    *(ushort8*)&Ab[awA] = ra0;
    #pragma unroll
    for (int t = 0; t < 8; t++)
      *(ushort8*)&Bb[SWZS(bwr + 16 * t, cj)] = rbv[t];
    __syncthreads();
    if (k0 + 32 < K) {
      ra0 = *(const ushort8*)(Ag + k0 + 32);
      #pragma unroll
      for (int t = 0; t < 8; t++)
        rbv[t] = *(const ushort8*)(Bg + (size_t)16 * t * K + k0 + 32);
    }
    bf16x8 af[2], bfr[8][2];
    #pragma unroll
    for (int hh = 0; hh < 2; hh++)
      af[hh] = *(const bf16x8*)&Ab[SWZS(wr * 32 + m32, 2 * hh + hi)];
    #pragma unroll
    for (int j = 0; j < 8; j++)
      #pragma unroll
      for (int hh = 0; hh < 2; hh++)
        bfr[j][hh] = *(const bf16x8*)&Bs[p * 16384 + SWZS(wc * 256 + j * 32 + m32, 2 * hh + hi)];
    #pragma unroll
    for (int hh = 0; hh < 2; hh++)
      #pragma unroll
      for (int j = 0; j < 8; j++)
        acc[j] = __builtin_amdgcn_mfma_f32_32x32x16_bf16(af[hh], bfr[j][hh], acc[j], 0, 0, 0);
    p ^= 1;
  }

  float bc[8], gc[8], bec[8];
  #pragma unroll
  for (int j = 0; j < 8; j++) {
    int col = wc * 256 + j * 32 + m32;
    bc[j] = bias[col]; gc[j] = g[col]; bec[j] = be[col];
  }

  // pass 1: xp/dv (recycle acc regs), partial sums over this wave-half's 256 cols
  #pragma unroll
  for (int pr = 0; pr < 8; pr++) {
    int re = wr * 32 + 4 * hi + 2 * (pr & 1) + 8 * (pr >> 1);   // even row in 0..63
    size_t ge = (size_t)(row0 + re) * N;
    float sx = 0.f, sxx = 0.f, sdv = 0.f, sxdv = 0.f;
    #pragma unroll
    for (int j = 0; j < 8; j++) {
      int col = wc * 256 + j * 32 + m32;
      float xp = acc[j][2 * pr]     + bc[j] + b2f(h[ge + col]);
      float dv = acc[j][2 * pr + 1]         + b2f(h[ge + N + col]);
      acc[j][2 * pr] = xp; acc[j][2 * pr + 1] = dv;
      sx += xp; sxx += xp * xp; sdv += dv; sxdv += xp * dv;
    }
    #pragma unroll
    for (int off = 1; off <= 16; off <<= 1) {   // reduce within 32-lane half
      sx   += __shfl_xor(sx, off, 64);
      sxx  += __shfl_xor(sxx, off, 64);
      sdv  += __shfl_xor(sdv, off, 64);
      sxdv += __shfl_xor(sxdv, off, 64);
    }
    if (m32 == 0) {
      int pid = re >> 1;
      red[pid][wc][0] = sx; red[pid][wc][1] = sxx;
      red[pid][wc][2] = sdv; red[pid][wc][3] = sxdv;
    }
  }
  __syncthreads();

  const float inv = 1.0f / 512.0f;
  float sl = 0.f;
  if (XATT) sl = *sc_p;
  #pragma unroll
  for (int pr = 0; pr < 8; pr++) {
    int re = wr * 32 + 4 * hi + 2 * (pr & 1) + 8 * (pr >> 1);
    int pid = re >> 1;
    float sx   = red[pid][0][0] + red[pid][1][0];
    float sxx  = red[pid][0][1] + red[pid][1][1];
    float sdv  = red[pid][0][2] + red[pid][1][2];
    float sxdv = red[pid][0][3] + red[pid][1][3];
    float m = sx * inv;
    float var = sxx * inv - m * m;
    float rstd = rsqrtf(var + 1e-5f);
    float dm = sdv * inv;
    float cm = (sxdv - m * sdv) * inv * rstd;   // mean(xhat*dv)
    size_t ge = (size_t)(row0 + re) * N;
    size_t bx_ = (size_t)((row0 + re) >> 1) * N;
    #pragma unroll
    for (int j = 0; j < 8; j++) {
      int col = wc * 256 + j * 32 + m32;
      float xp = acc[j][2 * pr], dv = acc[j][2 * pr + 1];
      float xh = (xp - m) * rstd;
      float y = xh * gc[j] + bec[j];
      if (XATT) y += sl * b2f(xatt[bx_ + col]);
      float dy = gc[j] * rstd * (dv - dm - xh * cm);
      h[ge + col]     = f2b(y);
      h[ge + N + col] = f2b(dy);
    }
  }
}

// ---------- wide GEMM for Wm1: 128x256 tile, wave 64x128, gelu-JVP epilogue ----------
__global__ __launch_bounds__(256, 2) void gemm_wide3_k(
    const unsigned short* __restrict__ A, const unsigned short* __restrict__ Bt,
    unsigned short* __restrict__ C, const float* __restrict__ bias,
    int M, int N, int K)
{
  __shared__ unsigned short As[2 * 128 * 32];   // 16 KB
  __shared__ unsigned short Bs[2 * 256 * 32];   // 32 KB
  const int tid  = threadIdx.x;
  const int lane = tid & 63;
  const int wave = tid >> 6;

  int bx = blockIdx.x, by = blockIdx.y;
  if ((gridDim.y & 7) == 0) {
    int lin = by * gridDim.x + bx;
    int xcd = lin & 7;
    int w   = lin >> 3;
    by = xcd * (gridDim.y >> 3) + w / gridDim.x;
    bx = w % gridDim.x;
  }
  const int row0 = by * 128;
  const int col0 = bx * 256;

  const int r0 = lane >> 2;
  const int cj = lane & 3;
  const unsigned short* Ag = A  + (size_t)(row0 + wave * 32 + r0) * K + cj * 8;
  const unsigned short* Bg = Bt + (size_t)(col0 + wave * 64 + r0) * K + cj * 8;
  const int awr = wave * 32 + r0;
  const int bwr = wave * 64 + r0;

  const int wr = wave >> 1, wc = wave & 1;
  const int m32 = lane & 31;
  const int hi  = lane >> 5;

  floatx16 acc[2][4];
  #pragma unroll
  for (int i = 0; i < 2; i++)
    #pragma unroll
    for (int j = 0; j < 4; j++) acc[i][j] = zero16();

  ushort8 ra0, ra1, rbv[4];
  ra0 = *(const ushort8*)(Ag);
  ra1 = *(const ushort8*)(Ag + (size_t)16 * K);
  #pragma unroll
  for (int t = 0; t < 4; t++)
    rbv[t] = *(const ushort8*)(Bg + (size_t)16 * t * K);

  int p = 0;
  for (int k0 = 0; k0 < K; k0 += 32) {
    unsigned short* Ab = &As[p * 4096];
    unsigned short* Bb = &Bs[p * 8192];
    *(ushort8*)&Ab[SWZS(awr, cj)]      = ra0;
    *(ushort8*)&Ab[SWZS(awr + 16, cj)] = ra1;
    #pragma unroll
    for (int t = 0; t < 4; t++)
      *(ushort8*)&Bb[SWZS(bwr + 16 * t, cj)] = rbv[t];
    __syncthreads();
    if (k0 + 32 < K) {
      ra0 = *(const ushort8*)(Ag + k0 + 32);
      ra1 = *(const ushort8*)(Ag + (size_t)16 * K + k0 + 32);
      #pragma unroll
      for (int t = 0; t < 4; t++)
        rbv[t] = *(const ushort8*)(Bg + (size_t)16 * t * K + k0 + 32);
    }
    bf16x8 af[2][2], bfr[4][2];
    #pragma unroll
    for (int i = 0; i < 2; i++)
      #pragma unroll
      for (int h = 0; h < 2; h++)
        af[i][h] = *(const bf16x8*)&Ab[SWZS(wr * 64 + i * 32 + m32, 2 * h + hi)];
    #pragma unroll
    for (int j = 0; j < 4; j++)
      #pragma unroll
      for (int h = 0; h < 2; h++)
        bfr[j][h] = *(const bf16x8*)&Bb[SWZS(wc * 128 + j * 32 + m32, 2 * h + hi)];
    #pragma unroll
    for (int h = 0; h < 2; h++)
      #pragma unroll
      for (int i = 0; i < 2; i++)
        #pragma unroll
        for (int j = 0; j < 4; j++)
          acc[i][j] = __builtin_amdgcn_mfma_f32_32x32x16_bf16(af[i][h], bfr[j][h], acc[i][j], 0, 0, 0);
    p ^= 1;
  }

  #pragma unroll
  for (int j = 0; j < 4; j++) {
    int col = col0 + wc * 128 + j * 32 + m32;
    float bb = bias[col];
    #pragma unroll
    for (int i = 0; i < 2; i++) {
      int rb = row0 + wr * 64 + i * 32 + 4 * hi;
      #pragma unroll
      for (int pr = 0; pr < 8; pr++) {
        int re = rb + 2 * (pr & 1) + 8 * (pr >> 1);
        float pv = acc[i][j][2 * pr] + bb;
        float tv = acc[i][j][2 * pr + 1];
        float cdf = 0.5f * (1.0f + erff(pv * 0.7071067811865475f));
        float pdf = 0.3989422804014327f * expf(-0.5f * pv * pv);
        C[(size_t)re * N + col]       = f2b(pv * cdf);
        C[(size_t)(re + 1) * N + col] = f2b((cdf + pv * pdf) * tv);
      }
    }
  }
}

// ---------- fused Wp2 GEMM + Euler update + Hutchinson + Abuf build (dbuf) ----------
__global__ __launch_bounds__(256) void gemm_vout_k(
    const unsigned short* __restrict__ A, const unsigned short* __restrict__ Bt,
    const float* __restrict__ bias, const float* __restrict__ u_cur,
    const float* __restrict__ u_next, float* __restrict__ zf,
    float* __restrict__ ldb, unsigned short* __restrict__ Abuf,
    int K, float dtv)
{
  constexpr int N = 128;
  __shared__ unsigned short As[2 * 128 * 32];
  __shared__ unsigned short Bs[2 * 128 * 32];
  __shared__ float red[64][2];
  const int tid = threadIdx.x, lane = tid & 63, wave = tid >> 6;
  const int row0 = blockIdx.x * 128;

  const int r0 = lane >> 2;
  const int cj = lane & 3;
  const unsigned short* Ag = A  + (size_t)(row0 + wave * 32 + r0) * K + cj * 8;
  const unsigned short* Bg = Bt + (size_t)(wave * 32 + r0) * K + cj * 8;
  const int aw0 = SWZS(wave * 32 + r0, cj);

  const int wr = wave >> 1, wc = wave & 1;
  const int m32 = lane & 31;
  const int hi  = lane >> 5;

  floatx16 acc[2][2];
  acc[0][0] = zero16(); acc[0][1] = zero16();
  acc[1][0] = zero16(); acc[1][1] = zero16();

  ushort8 ra0, ra1, rb0, rb1;
  ra0 = *(const ushort8*)(Ag);
  ra1 = *(const ushort8*)(Ag + (size_t)16 * K);
  rb0 = *(const ushort8*)(Bg);
  rb1 = *(const ushort8*)(Bg + (size_t)16 * K);

  int p = 0;
  for (int k0 = 0; k0 < K; k0 += 32) {
    unsigned short* Ab = &As[p * 4096];
    unsigned short* Bb = &Bs[p * 4096];
    *(ushort8*)(Ab + aw0)           = ra0;
    *(ushort8*)(Ab + aw0 + 16 * 32) = ra1;
    *(ushort8*)(Bb + aw0)           = rb0;
    *(ushort8*)(Bb + aw0 + 16 * 32) = rb1;
    __syncthreads();
    if (k0 + 32 < K) {
      ra0 = *(const ushort8*)(Ag + k0 + 32);
      ra1 = *(const ushort8*)(Ag + (size_t)16 * K + k0 + 32);
      rb0 = *(const ushort8*)(Bg + k0 + 32);
      rb1 = *(const ushort8*)(Bg + (size_t)16 * K + k0 + 32);
    }
    bf16x8 af[2][2], bfr[2][2];
    #pragma unroll
    for (int i = 0; i < 2; i++)
      #pragma unroll
      for (int h = 0; h < 2; h++)
        af[i][h] = *(const bf16x8*)&Ab[SWZS(wr * 64 + i * 32 + m32, 2 * h + hi)];
    #pragma unroll
    for (int j = 0; j < 2; j++)
      #pragma unroll
      for (int h = 0; h < 2; h++)
        bfr[j][h] = *(const bf16x8*)&Bb[SWZS(wc * 64 + j * 32 + m32, 2 * h + hi)];
    #pragma unroll
    for (int h = 0; h < 2; h++)
      #pragma unroll
      for (int i = 0; i < 2; i++)
        #pragma unroll
        for (int j = 0; j < 2; j++)
          acc[i][j] = __builtin_amdgcn_mfma_f32_32x32x16_bf16(af[i][h], bfr[j][h], acc[i][j], 0, 0, 0);
    p ^= 1;
  }

  #pragma unroll
  for (int i = 0; i < 2; i++) {
    #pragma unroll
    for (int pr = 0; pr < 8; pr++) {
      int re_loc = wr * 64 + i * 32 + 4 * hi + 2 * (pr & 1) + 8 * (pr >> 1);
      size_t growe = (size_t)(row0 + re_loc);
      size_t b = growe >> 1;           // pair (batch row) index
      float dacc = 0.f;
      #pragma unroll
      for (int j = 0; j < 2; j++) {
        int col = wc * 64 + j * 32 + m32;
        float v  = acc[i][j][2 * pr] + bias[col];
        float Ju = acc[i][j][2 * pr + 1];
        float z = zf[b * N + col] + v * dtv;
        zf[b * N + col] = z;
        Abuf[growe * N + col] = f2b(z);
        if (u_next) Abuf[(growe + 1) * N + col] = f2b(u_next[b * N + col]);
        dacc += u_cur[b * N + col] * Ju;
      }
      #pragma unroll
      for (int off = 1; off <= 16; off <<= 1) dacc += __shfl_xor(dacc, off, 64);
      if (m32 == 0) red[re_loc >> 1][wc] = dacc;
    }
  }
  __syncthreads();
  if (tid < 64) ldb[(row0 >> 1) + tid] += (red[tid][0] + red[tid][1]) * dtv;
}

// ---------- transpose+cast: W[K,N] f32 -> Wt[N,K] bf16 (batched over z) ----------
__global__ void transpose_cast_k(const float* __restrict__ W,
                                 unsigned short* __restrict__ Wt, int K, int N)
{
  __shared__ float tile[32][33];
  size_t off = (size_t)blockIdx.z * K * N;
  const float* Wp = W + off;
  unsigned short* Wtp = Wt + off;
  int bx = blockIdx.x, by = blockIdx.y;
  int tx = threadIdx.x, ty = threadIdx.y;
  #pragma unroll
  for (int i = ty; i < 32; i += 8)
    tile[i][tx] = Wp[(size_t)(by * 32 + i) * N + bx * 32 + tx];
  __syncthreads();
  #pragma unroll
  for (int i = ty; i < 32; i += 8)
    Wtp[(size_t)(bx * 32 + i) * K + by * 32 + tx] = f2b(tile[tx][i]);
}

// ---------- zero-init ----------
__global__ __launch_bounds__(256) void zero_k(float* __restrict__ p, int n) {
  int i = (int)(blockIdx.x * blockDim.x + threadIdx.x);
  if (i < n) p[i] = 0.f;
}

// ---------- combined bias (k-split + atomics) ----------
__global__ __launch_bounds__(256) void combine_bias_k(
    const float* __restrict__ bvp, const float* __restrict__ Wb,
    const float* __restrict__ bo, float* __restrict__ bout, int H)
{
  int out = blockIdx.x * blockDim.x + threadIdx.x;
  int l   = blockIdx.y;
  int kc  = blockIdx.z;
  const float* A2 = Wb + (size_t)l * H * H;
  float s = (kc == 0) ? bo[(size_t)l * H + out] : 0.f;
  int kend = (kc + 1) * 64;
  for (int k = kc * 64; k < kend; k++) s += bvp[(size_t)l * H + k] * A2[(size_t)k * H + out];
  atomicAdd(&bout[(size_t)l * H + out], s);
}

// ---------- f32 -> bf16 cast ----------
__global__ __launch_bounds__(256) void cast_k(const float* __restrict__ in,
                                              unsigned short* __restrict__ out, size_t n) {
  size_t i = blockIdx.x * blockDim.x + threadIdx.x;
  if (i < n) out[i] = f2b(in[i]);
}

// ---------- all S time embeddings: tvecs[s][H] ----------
__global__ __launch_bounds__(512) void temb_all_k(
    const float* __restrict__ Wt1, const float* __restrict__ bt1,
    const float* __restrict__ Wt2, const float* __restrict__ bt2,
    float dtv, float* __restrict__ tvecs, int H)
{
  __shared__ float e[512];
  int j = threadIdx.x;
  float t = fminf(fmaxf((float)blockIdx.x * dtv, 0.f), 1.f);
  e[j] = gelu_f(t * Wt1[j] + bt1[j]);
  __syncthreads();
  float s = bt2[j];
  for (int k = 0; k < H; k++) s += e[k] * Wt2[(size_t)k * H + j];
  tvecs[(size_t)blockIdx.x * H + j] = s;
}

// ---------- init: zf=x, ld=0, Abuf interleaved [z;u] ----------
__global__ __launch_bounds__(256) void init_k(
    const float* __restrict__ x, const float* __restrict__ u0,
    float* __restrict__ zf, float* __restrict__ ld,
    unsigned short* __restrict__ Abuf, int BF, int Bsz, int F)
{
  int i = (int)(blockIdx.x * blockDim.x + threadIdx.x);
  if (i < BF) {
    int r = i / F, c = i - r * F;
    float v = x[i];
    zf[i] = v;
    Abuf[(size_t)(2 * r) * F + c]     = f2b(v);
    Abuf[(size_t)(2 * r + 1) * F + c] = f2b(u0[i]);
  }
  if (i < Bsz) ld[i] = 0.f;
}

// ---------- write outputs ----------
__global__ __launch_bounds__(256) void final_k(
    const float* __restrict__ zf, const float* __restrict__ ld,
    float* __restrict__ out, int BF, int Bsz)
{
  int i = (int)(blockIdx.x * blockDim.x + threadIdx.x);
  if (i < BF) out[i] = zf[i];
  if (i < Bsz) out[BF + i] = ld[i];
}

extern "C" void kernel_launch(void* const* d_in, const int* in_sizes, int n_in,
                              void* d_out, int out_size, void* d_ws, size_t ws_size,
                              hipStream_t stream) {
  constexpr int B = 8192, F = 128, C = 256, H = 512, L = 4, S = 10;
  constexpr int B2 = 2 * B;
  constexpr int BF = B * F;
  const float dtv = 1.0f / S;

  const float* x    = (const float*)d_in[0];
  const float* ctxI = (const float*)d_in[1];
  const float* u    = (const float*)d_in[2];
  const float* Wi   = (const float*)d_in[3];
  const float* bi   = (const float*)d_in[4];
  const float* Wt1  = (const float*)d_in[5];
  const float* bt1  = (const float*)d_in[6];
  const float* Wt2  = (const float*)d_in[7];
  const float* bt2  = (const float*)d_in[8];
  const float* Wc1  = (const float*)d_in[9];
  const float* bc1  = (const float*)d_in[10];
  const float* Wc2  = (const float*)d_in[11];
  const float* bc2  = (const float*)d_in[12];
  const float* Wv   = (const float*)d_in[13];
  const float* bv   = (const float*)d_in[14];
  const float* Woa  = (const float*)d_in[15];
  const float* boa  = (const float*)d_in[16];
  const float* g1   = (const float*)d_in[17];
  const float* be1  = (const float*)d_in[18];
  const float* Wm1  = (const float*)d_in[19];
  const float* bm1  = (const float*)d_in[20];
  const float* Wm2  = (const float*)d_in[21];
  const float* bm2  = (const float*)d_in[22];
  const float* g2   = (const float*)d_in[23];
  const float* be2  = (const float*)d_in[24];
  const float* Wcv  = (const float*)d_in[25];
  const float* bcv  = (const float*)d_in[26];
  const float* Wco  = (const float*)d_in[27];
  const float* bco  = (const float*)d_in[28];
  const float* scal = (const float*)d_in[29];
  const float* Wp1  = (const float*)d_in[30];
  const float* bp1  = (const float*)d_in[31];
  const float* Wp2  = (const float*)d_in[32];
  const float* bp2  = (const float*)d_in[33];

  // ---- workspace layout ----
  char* wp = (char*)d_ws;
  auto alloc = [&](size_t bytes) -> void* {
    void* r = (void*)wp;
    wp += (bytes + 255) & ~(size_t)255;
    return r;
  };
  unsigned short* wWit  = (unsigned short*)alloc((size_t)H * F * 2);
  unsigned short* wWc1t = (unsigned short*)alloc((size_t)2 * H * C * 2);
  unsigned short* wWc2t = (unsigned short*)alloc((size_t)H * 2 * H * 2);
  unsigned short* wWvoT = (unsigned short*)alloc((size_t)L * H * H * 2);
  unsigned short* wCtxT = (unsigned short*)alloc((size_t)L * H * H * 2);
  unsigned short* wWm1t = (unsigned short*)alloc((size_t)L * 4 * H * H * 2);
  unsigned short* wWm2t = (unsigned short*)alloc((size_t)L * H * 4 * H * 2);
  unsigned short* wWp1t = (unsigned short*)alloc((size_t)H * H * 2);
  unsigned short* wWp2t = (unsigned short*)alloc((size_t)F * H * 2);
  unsigned short* wOaT  = (unsigned short*)alloc((size_t)L * H * H * 2);
  unsigned short* wCoT  = (unsigned short*)alloc((size_t)L * H * H * 2);
  unsigned short* wVb   = (unsigned short*)alloc((size_t)L * H * H * 2);
  unsigned short* wCvb  = (unsigned short*)alloc((size_t)L * H * H * 2);
  float* bcomb          = (float*)alloc((size_t)2 * L * H * 4);  // bvo | cbvo
  float* bvo  = bcomb;
  float* cbvo = bcomb + (size_t)L * H;
  float* tvecs          = (float*)alloc((size_t)S * H * 4);
  unsigned short* ctxc  = (unsigned short*)alloc((size_t)B * C * 2);
  unsigned short* Abuf  = (unsigned short*)alloc((size_t)B2 * F * 2);
  unsigned short* hbuf  = (unsigned short*)alloc((size_t)B2 * H * 2);
  unsigned short* tmp2  = (unsigned short*)alloc((size_t)B2 * H * 2);
  unsigned short* mbuf  = (unsigned short*)alloc((size_t)B2 * 4 * H * 2);
  unsigned short* xattb = (unsigned short*)alloc((size_t)L * B * H * 2);
  float* zf             = (float*)alloc((size_t)B * F * 4);
  float* ldb            = (float*)alloc((size_t)B * 4);
  (void)ws_size; (void)in_sizes; (void)n_in; (void)out_size;

  auto T = [&](const float* W, unsigned short* Wt, int K, int N, int Lz) {
    dim3 g(N / 32, K / 32, Lz);
    transpose_cast_k<<<g, dim3(32, 8), 0, stream>>>(W, Wt, K, N);
  };
  auto G = [&](int mode, const unsigned short* A, const unsigned short* Bt, void* Cc,
               const float* bias, const float* bias2, int M, int N, int K) {
    dim3 g(N / 128, M / 128);
    switch (mode) {
      case 0: gemm_bt_k<0><<<g, 256, 0, stream>>>(A, Bt, Cc, bias, bias2, M, N, K); break;
      case 1: gemm_bt_k<1><<<g, 256, 0, stream>>>(A, Bt, Cc, bias, bias2, M, N, K); break;
      case 2: gemm_bt_k<2><<<g, 256, 0, stream>>>(A, Bt, Cc, bias, bias2, M, N, K); break;
      case 3: gemm_bt_k<3><<<g, 256, 0, stream>>>(A, Bt, Cc, bias, bias2, M, N, K); break;
    }
  };

  // ---- weight prep ----
  T(Wi,  wWit,  F, H, 1);
  T(Wc1, wWc1t, C, 2 * H, 1);
  T(Wc2, wWc2t, 2 * H, H, 1);
  T(Wm1, wWm1t, H, 4 * H, L);
  T(Wm2, wWm2t, 4 * H, H, L);
  T(Wp1, wWp1t, H, H, 1);
  T(Wp2, wWp2t, H, F, 1);
  T(Woa, wOaT, H, H, L);
  T(Wco, wCoT, H, H, L);
  cast_k<<<((size_t)L * H * H + 255) / 256, 256, 0, stream>>>(Wv,  wVb,  (size_t)L * H * H);
  cast_k<<<((size_t)L * H * H + 255) / 256, 256, 0, stream>>>(Wcv, wCvb, (size_t)L * H * H);
  for (int l = 0; l < L; l++) {
    size_t o2 = (size_t)l * H * H;
    G(0, wOaT + o2, wVb  + o2, wWvoT + o2, nullptr, nullptr, H, H, H);
    G(0, wCoT + o2, wCvb + o2, wCtxT + o2, nullptr, nullptr, H, H, H);
  }
  zero_k<<<(2 * L * H + 255) / 256, 256, 0, stream>>>(bcomb, 2 * L * H);
  combine_bias_k<<<dim3(H / 256, L, H / 64), 256, 0, stream>>>(bv,  Woa, boa, bvo,  H);
  combine_bias_k<<<dim3(H / 256, L, H / 64), 256, 0, stream>>>(bcv, Wco, bco, cbvo, H);

  // ---- context path (z-independent): xatt[l] = ctx @ (Wcv@Wco) + (bcv@Wco+bco) ----
  cast_k<<<(B * C + 255) / 256, 256, 0, stream>>>(ctxI, ctxc, (size_t)B * C);
  G(1, ctxc, wWc1t, mbuf, bc1, nullptr, B, 2 * H, C);           // gelu fused
  G(0, mbuf, wWc2t, tmp2, bc2, nullptr, B, H, 2 * H);
  for (int l = 0; l < L; l++)
    G(0, tmp2, wCtxT + (size_t)l * H * H, xattb + (size_t)l * B * H,
      cbvo + l * H, nullptr, B, H, H);

  temb_all_k<<<S, H, 0, stream>>>(Wt1, bt1, Wt2, bt2, dtv, tvecs, H);
  init_k<<<(BF + 255) / 256, 256, 0, stream>>>(x, u, zf, ldb, Abuf, BF, B, F);

  // ---- S Euler steps; rows interleaved (2i primal, 2i+1 tangent) ----
  for (int s = 0; s < S; s++) {
    G(2, Abuf, wWit, hbuf, bi, tvecs + (size_t)s * H, B2, H, F);
    for (int l = 0; l < L; l++) {
      size_t o2 = (size_t)l * H * H;
      size_t om = (size_t)l * 4 * H * H;
      gemm_ln_k<false><<<B2 / 64, 256, 0, stream>>>(
          hbuf, wWvoT + o2, hbuf, bvo + l * H, g1 + l * H, be1 + l * H,
          nullptr, nullptr, H);
      gemm_wide3_k<<<dim3(4 * H / 256, B2 / 128), 256, 0, stream>>>(
          hbuf, wWm1t + om, mbuf, bm1 + (size_t)l * 4 * H, B2, 4 * H, H);
      gemm_ln_k<true><<<B2 / 64, 256, 0, stream>>>(
          mbuf, wWm2t + om, hbuf, bm2 + l * H, g2 + l * H, be2 + l * H,
          xattb + (size_t)l * B * H, scal + l, 4 * H);
    }
    G(3, hbuf, wWp1t, tmp2, bp1, nullptr, B2, H, H);
    const float* u_cur = u + (size_t)s * BF;
    const float* u_next = (s + 1 < S) ? u + (size_t)(s + 1) * BF : nullptr;
    gemm_vout_k<<<B2 / 128, 256, 0, stream>>>(
        tmp2, wWp2t, bp2, u_cur, u_next, zf, ldb, Abuf, H, dtv);
  }

  final_k<<<(BF + 255) / 256, 256, 0, stream>>>(zf, ldb, (float*)d_out, BF, B);
}